// Round 20
// baseline (125.806 us; speedup 1.0000x reference)
//
#include <hip/hip_runtime.h>
#include <hip/hip_bf16.h>
#include <math.h>

#define WORDC 30000
#define F_TOT 80000
#define NTOK  2048
#define DMODEL 256
#define FFDIM 512
#define NHEAD 8
#define HDIM  32
#define SEQL  64

typedef __attribute__((ext_vector_type(8))) short bf16x8;
typedef __attribute__((ext_vector_type(8))) unsigned short u16x8;
typedef __attribute__((ext_vector_type(4))) float f32x4;

__device__ __forceinline__ unsigned short f32_to_bf16_rne(float x) {
    unsigned int u = __float_as_uint(x);
    unsigned int r = (u + 0x7FFFu + ((u >> 16) & 1u)) >> 16;
    return (unsigned short)r;
}

__device__ __forceinline__ u16x8 cvt8(float4 a, float4 b) {
    u16x8 v;
    v[0] = f32_to_bf16_rne(a.x); v[1] = f32_to_bf16_rne(a.y);
    v[2] = f32_to_bf16_rne(a.z); v[3] = f32_to_bf16_rne(a.w);
    v[4] = f32_to_bf16_rne(b.x); v[5] = f32_to_bf16_rne(b.y);
    v[6] = f32_to_bf16_rne(b.z); v[7] = f32_to_bf16_rne(b.w);
    return v;
}

// load one MFMA B-fragment from fragment-major packed weights:
// layout elems[((ntile*KT + ktile)*64 + lane)*8], row = ntile*16+(lane&15),
// k = ktile*32+(lane>>4)*8.
__device__ __forceinline__ bf16x8 ldfrag(const unsigned short* F, int ntile,
                                          int KT, int ktile, int lane) {
    return *(const bf16x8*)&F[(((long)(ntile * KT + ktile) * 64 + lane) << 3)];
}

// ---------------------------------------------------------------------------
// Parallel bitmap mark. Grid 56; bm zeroed via hipMemsetAsync first.
// ---------------------------------------------------------------------------
__global__ __launch_bounds__(256) void mark_feats_par(
    const int* __restrict__ word_idx,
    const int* __restrict__ ngram_idx,
    unsigned int* __restrict__ bm)
{
    int i = blockIdx.x * 256 + threadIdx.x;
    int f;
    if (i < NTOK)                f = word_idx[i];
    else if (i < NTOK * 7)       f = WORDC + ngram_idx[i - NTOK];
    else                         return;
    atomicOr(&bm[f >> 5], 1u << (f & 31));
}

// ---------------------------------------------------------------------------
// Transpose fc1_w (store-pruned) + repack transformer weights into
// fragment-major bf16. Grid: [0,8000) transpose, [8000,8768) repack.
// ---------------------------------------------------------------------------
__global__ __launch_bounds__(256) void transpose_cvt(
    const float* __restrict__ fc1_w,
    unsigned short* __restrict__ fc1T,
    const unsigned int* __restrict__ bm,
    const float* __restrict__ s0, const float* __restrict__ s1,
    const float* __restrict__ s2, const float* __restrict__ s3,
    unsigned short* __restrict__ d0, unsigned short* __restrict__ d1,
    unsigned short* __restrict__ d2, unsigned short* __restrict__ d3)
{
    __shared__ float tile[320][17];
    const int bid = blockIdx.x;
    const int tid = threadIdx.x;

    if (bid < 8000) {
        const int f0 = (bid % 250) * 320;
        const int j0 = (bid / 250) * 16;

        #pragma unroll
        for (int it = 0; it < 5; ++it) {
            int idx = it * 256 + tid;
            int jr  = idx / 80;
            int c4  = idx - jr * 80;
            float4 v = *(const float4*)&fc1_w[(long)(j0 + jr) * F_TOT + f0 + c4 * 4];
            tile[c4 * 4 + 0][jr] = v.x;
            tile[c4 * 4 + 1][jr] = v.y;
            tile[c4 * 4 + 2][jr] = v.z;
            tile[c4 * 4 + 3][jr] = v.w;
        }
        __syncthreads();

        for (int f = tid; f < 320; f += 256) {
            int fg = f0 + f;
            if ((bm[fg >> 5] >> (fg & 31)) & 1u) {
                u16x8 lo, hi;
                #pragma unroll
                for (int j = 0; j < 8; ++j) {
                    lo[j] = f32_to_bf16_rne(tile[f][j]);
                    hi[j] = f32_to_bf16_rne(tile[f][j + 8]);
                }
                *(u16x8*)&fc1T[(long)fg * FFDIM + j0]     = lo;
                *(u16x8*)&fc1T[(long)fg * FFDIM + j0 + 8] = hi;
            }
        }
    } else {
        // fragment-major repack: one fragment (8 elems) per thread.
        // tensor frag counts: qkv 49152 | out 16384 | ff1 65536 | ff2 65536
        long fid = (long)(bid - 8000) * 256 + tid;   // 0..196607
        const float* src; unsigned short* dst; int K; long base;
        if (fid < 49152)        { src = s0; dst = d0; K = 256;  base = fid; }
        else if (fid < 65536)   { src = s1; dst = d1; K = 256;  base = fid - 49152; }
        else if (fid < 131072)  { src = s2; dst = d2; K = 256;  base = fid - 65536; }
        else                    { src = s3; dst = d3; K = 1024; base = fid - 131072; }
        int lane = (int)(base & 63);
        long t   = base >> 6;
        int KT   = K >> 5;
        int ntile = (int)(t / KT);
        int ktile = (int)(t - (long)ntile * KT);
        int row = ntile * 16 + (lane & 15);
        int k   = ktile * 32 + (lane >> 4) * 8;
        const float* sp = src + (long)row * K + k;
        u16x8 v;
        #pragma unroll
        for (int j = 0; j < 8; ++j) v[j] = f32_to_bf16_rne(sp[j]);
        *(u16x8*)&dst[base << 3] = v;
    }
}

// ---------------------------------------------------------------------------
// Gather: fixed-trip masked 7-feat sum -> relu -> fc2. (R14 proven)
// ---------------------------------------------------------------------------
__global__ __launch_bounds__(256) void embed_gather(
    const int* __restrict__ word_idx,
    const int* __restrict__ ngram_idx,
    const unsigned short* __restrict__ fc1_wT,
    const float* __restrict__ fc1_b,
    const float* __restrict__ fc2_w,
    const float* __restrict__ fc2_b,
    float* __restrict__ x)
{
    __shared__ int   feats[8][8];
    __shared__ float wmsk[8][8];
    __shared__ float x1[8][FFDIM];

    const int t0  = blockIdx.x * 8;
    const int tid = threadIdx.x;

    if (tid < 8) {
        int t = t0 + tid;
        feats[tid][0] = word_idx[t];
        wmsk[tid][0]  = 1.f;
        #pragma unroll
        for (int k = 0; k < 6; ++k) {
            int f = WORDC + ngram_idx[t * 6 + k];
            bool dup = false;
            for (int s = 1; s <= k; ++s)
                if (feats[tid][s] == f) dup = true;
            feats[tid][1 + k] = f;
            wmsk[tid][1 + k]  = dup ? 0.f : 1.f;
        }
    }
    __syncthreads();

    const float2 bb = *(const float2*)&fc1_b[tid * 2];
    #pragma unroll
    for (int tt = 0; tt < 8; ++tt) {
        float a0 = bb.x, a1 = bb.y;
        #pragma unroll
        for (int s = 0; s < 7; ++s) {
            unsigned int wrd = *(const unsigned int*)
                &fc1_wT[(long)feats[tt][s] * FFDIM + tid * 2];
            float m = wmsk[tt][s];
            a0 += m * __uint_as_float((wrd & 0xFFFFu) << 16);
            a1 += m * __uint_as_float(wrd & 0xFFFF0000u);
        }
        x1[tt][tid * 2 + 0] = fmaxf(a0, 0.f);
        x1[tt][tid * 2 + 1] = fmaxf(a1, 0.f);
    }
    __syncthreads();

    const int d = tid;
    float acc[8];
    float cb = fc2_b[d];
    #pragma unroll
    for (int tt = 0; tt < 8; ++tt) acc[tt] = cb;
    const float* wrow = fc2_w + d * FFDIM;
    for (int k = 0; k < FFDIM; ++k) {
        float wv = wrow[k];
        #pragma unroll
        for (int tt = 0; tt < 8; ++tt) acc[tt] += wv * x1[tt][k];
    }
    #pragma unroll
    for (int tt = 0; tt < 8; ++tt)
        x[(t0 + tt) * DMODEL + d] = acc[tt];
}

// ---------------------------------------------------------------------------
// Fused per-(b,h) QKV GEMM + MFMA attention. W direct fragment loads.
// (R18 proven, ~2.5us/dispatch)
// ---------------------------------------------------------------------------
__global__ __launch_bounds__(512, 4) void fused_qkv_attn(
    const float* __restrict__ x,
    const unsigned short* __restrict__ WqF,  // layer qkv frag-packed [768][256]
    const float* __restrict__ bq,
    float* __restrict__ o)
{
    __shared__ unsigned short sA[64 * 264];
    __shared__ unsigned short sQ[64 * 40];
    __shared__ unsigned short sK[64 * 40];
    __shared__ unsigned short sVt[32 * 72];
    __shared__ unsigned short sP[64 * 72];
    __shared__ float sfmx[2][64];
    __shared__ float sfsm[2][64];

    const int b = blockIdx.x >> 3;
    const int h = blockIdx.x & 7;
    const int tid  = threadIdx.x;
    const int lane = tid & 63;
    const int w    = tid >> 6;          // 0..7
    const int rg   = w & 3;             // query-row group
    const int ch   = w >> 2;            // col half
    const int fr   = lane & 15;
    const int ksub = lane >> 4;
    const int row0 = b * SEQL;

    int nt[3];
    #pragma unroll
    for (int ni = 0; ni < 3; ++ni) {
        int c = ch * 48 + ni * 16;
        int part = c >> 5, pcb = c & 31;
        nt[ni] = (part * 256 + h * HDIM + pcb) >> 4;
    }

    #pragma unroll
    for (int j = 0; j < 4; ++j) {
        int c = j * 512 + tid;
        int row = c >> 5, c8 = c & 31;
        const float* ap = &x[(long)(row0 + row) * DMODEL + c8 * 8];
        float4 a0 = *(const float4*)ap;
        float4 a1 = *(const float4*)(ap + 4);
        *(u16x8*)&sA[row * 264 + c8 * 8] = cvt8(a0, a1);
    }

    bf16x8 wf[2][2][3];
    #pragma unroll
    for (int kk = 0; kk < 2; ++kk)
        #pragma unroll
        for (int ni = 0; ni < 3; ++ni)
            wf[0][kk][ni] = ldfrag(WqF, nt[ni], 8, kk, lane);
    #pragma unroll
    for (int kk = 0; kk < 2; ++kk)
        #pragma unroll
        for (int ni = 0; ni < 3; ++ni)
            wf[1][kk][ni] = ldfrag(WqF, nt[ni], 8, 2 + kk, lane);

    __syncthreads();   // sA ready

    f32x4 acc[3] = {};
    #pragma unroll
    for (int t = 0; t < 4; ++t) {
        const int cur = t & 1;
        #pragma unroll
        for (int kk = 0; kk < 2; ++kk) {
            bf16x8 af = *(bf16x8*)&sA[(rg * 16 + fr) * 264 + t * 64 + kk * 32 + ksub * 8];
            #pragma unroll
            for (int ni = 0; ni < 3; ++ni)
                acc[ni] = __builtin_amdgcn_mfma_f32_16x16x32_bf16(af, wf[cur][kk][ni], acc[ni], 0, 0, 0);
        }
        if (t + 2 < 4) {
            #pragma unroll
            for (int kk = 0; kk < 2; ++kk)
                #pragma unroll
                for (int ni = 0; ni < 3; ++ni)
                    wf[cur][kk][ni] = ldfrag(WqF, nt[ni], 8, (t + 2) * 2 + kk, lane);
        }
    }

    const float scale = 0.17677669529663687f;   // 1/sqrt(32)
    #pragma unroll
    for (int ni = 0; ni < 3; ++ni) {
        int c = ch * 48 + ni * 16 + fr;
        int part = c >> 5, pc = c & 31;
        float bv = bq[part * 256 + h * HDIM + pc];
        #pragma unroll
        for (int r = 0; r < 4; ++r) {
            int row = rg * 16 + ksub * 4 + r;
            float v = acc[ni][r] + bv;
            if (part == 0)      sQ[row * 40 + pc] = f32_to_bf16_rne(v * scale);
            else if (part == 1) sK[row * 40 + pc] = f32_to_bf16_rne(v);
            else                sVt[pc * 72 + row] = f32_to_bf16_rne(v);
        }
    }
    __syncthreads();

    f32x4 s4[2];
    {
        bf16x8 afq = *(bf16x8*)&sQ[(rg * 16 + fr) * 40 + ksub * 8];
        #pragma unroll
        for (int ni = 0; ni < 2; ++ni) {
            bf16x8 bfk = *(bf16x8*)&sK[(ch * 32 + ni * 16 + fr) * 40 + ksub * 8];
            f32x4 z = {};
            s4[ni] = __builtin_amdgcn_mfma_f32_16x16x32_bf16(afq, bfk, z, 0, 0, 0);
        }
    }

    #pragma unroll
    for (int r = 0; r < 4; ++r) {
        float m = fmaxf(s4[0][r], s4[1][r]);
        m = fmaxf(m, __shfl_xor(m, 1));
        m = fmaxf(m, __shfl_xor(m, 2));
        m = fmaxf(m, __shfl_xor(m, 4));
        m = fmaxf(m, __shfl_xor(m, 8));
        if (fr == 0) sfmx[ch][rg * 16 + ksub * 4 + r] = m;
    }
    __syncthreads();
    float minv[4];
    #pragma unroll
    for (int r = 0; r < 4; ++r) {
        int row = rg * 16 + ksub * 4 + r;
        float m = fmaxf(sfmx[0][row], sfmx[1][row]);
        float p0 = __expf(s4[0][r] - m);
        float p1 = __expf(s4[1][r] - m);
        sP[row * 72 + ch * 32 + fr]      = f32_to_bf16_rne(p0);
        sP[row * 72 + ch * 32 + 16 + fr] = f32_to_bf16_rne(p1);
        float s = p0 + p1;
        s += __shfl_xor(s, 1);
        s += __shfl_xor(s, 2);
        s += __shfl_xor(s, 4);
        s += __shfl_xor(s, 8);
        if (fr == 0) sfsm[ch][row] = s;
    }
    __syncthreads();
    #pragma unroll
    for (int r = 0; r < 4; ++r) {
        int row = rg * 16 + ksub * 4 + r;
        minv[r] = 1.f / (sfsm[0][row] + sfsm[1][row]);
    }

    f32x4 o4 = {};
    #pragma unroll
    for (int kc = 0; kc < 2; ++kc) {
        bf16x8 afp = *(bf16x8*)&sP[(rg * 16 + fr) * 72 + kc * 32 + ksub * 8];
        bf16x8 bfv = *(bf16x8*)&sVt[(ch * 16 + fr) * 72 + kc * 32 + ksub * 8];
        o4 = __builtin_amdgcn_mfma_f32_16x16x32_bf16(afp, bfv, o4, 0, 0, 0);
    }
    #pragma unroll
    for (int r = 0; r < 4; ++r) {
        int row = row0 + rg * 16 + ksub * 4 + r;
        o[(long)row * DMODEL + h * HDIM + ch * 16 + fr] = o4[r] * minv[r];
    }
}

// ---------------------------------------------------------------------------
// Fused out-proj + LN1 + FFN + LN2, BM=16 rows, 1024 thr / 16 waves.
// Wave owns a 16-col tile (ni=1). W direct fragment loads; same per-block
// weight traffic as R19 but 2x wave parallelism for latency hiding.
// ---------------------------------------------------------------------------
__global__ __launch_bounds__(1024) void outln_ffn(
    const float* __restrict__ attn_raw,
    const unsigned short* __restrict__ WoF,  // frag-packed [256][256]
    const float* __restrict__ bo,
    const float* __restrict__ g1, const float* __restrict__ b1t,
    const unsigned short* __restrict__ W1F,  // frag-packed [1024][256]
    const float* __restrict__ b1,
    const unsigned short* __restrict__ W2F,  // frag-packed [256][1024]
    const float* __restrict__ b2,
    const float* __restrict__ g2, const float* __restrict__ b2t,
    float* __restrict__ x)                   // residual in, final out
{
    __shared__ unsigned short sA[16 * 264];
    __shared__ float xnf[16 * 264];
    __shared__ unsigned short x1s[16 * 1032];
    __shared__ float redS[16][16];
    __shared__ float redQ[16][16];

    const int tid  = threadIdx.x;
    const int lane = tid & 63;
    const int w    = tid >> 6;          // 0..15
    const int fr   = lane & 15;
    const int ksub = lane >> 4;
    const int m0   = blockIdx.x * 16;
    const int col  = w * 16 + fr;       // this thread's output col (<256)

    // stage attn_raw rows 0..15 (bf16): 512 chunks, threads 0..511
    if (tid < 512) {
        int row = tid >> 5, c8 = tid & 31;
        const float* ap = &attn_raw[(long)(m0 + row) * DMODEL + c8 * 8];
        float4 a0 = *(const float4*)ap;
        float4 a1 = *(const float4*)(ap + 4);
        *(u16x8*)&sA[row * 264 + c8 * 8] = cvt8(a0, a1);
    }

    // depth-2 Wo fragment prefetch (ntile = w, KT=8)
    bf16x8 wf[2][2];
    #pragma unroll
    for (int kk = 0; kk < 2; ++kk) {
        wf[0][kk] = ldfrag(WoF, w, 8, kk, lane);
        wf[1][kk] = ldfrag(WoF, w, 8, 2 + kk, lane);
    }

    __syncthreads();

    // ---- phase A: out-projection ----
    f32x4 acc = {};
    #pragma unroll
    for (int t = 0; t < 4; ++t) {
        const int cur = t & 1;
        #pragma unroll
        for (int kk = 0; kk < 2; ++kk) {
            bf16x8 af = *(bf16x8*)&sA[fr * 264 + t * 64 + kk * 32 + ksub * 8];
            acc = __builtin_amdgcn_mfma_f32_16x16x32_bf16(af, wf[cur][kk], acc, 0, 0, 0);
        }
        if (t + 2 < 4) {
            #pragma unroll
            for (int kk = 0; kk < 2; ++kk)
                wf[cur][kk] = ldfrag(WoF, w, 8, (t + 2) * 2 + kk, lane);
        }
    }

    float vres[4];
    {
        float bv = bo[col];
        #pragma unroll
        for (int r = 0; r < 4; ++r) {
            int rl = ksub * 4 + r;
            vres[r] = acc[r] + bv + x[(long)(m0 + rl) * DMODEL + col];
        }
    }

    // prefetch W1 steps 0,1 (ntile = w for nc=0) while LN reduces
    bf16x8 wc[2], wn[2], wn2[2];
    #pragma unroll
    for (int kk = 0; kk < 2; ++kk) {
        wc[kk] = ldfrag(W1F, w, 8, kk, lane);
        wn[kk] = ldfrag(W1F, w, 8, 2 + kk, lane);
    }

    #pragma unroll
    for (int r = 0; r < 4; ++r) {
        float s  = vres[r];
        float qq = vres[r] * vres[r];
        #pragma unroll
        for (int mask = 1; mask < 16; mask <<= 1) {
            s  += __shfl_xor(s, mask);
            qq += __shfl_xor(qq, mask);
        }
        if (fr == 0) {
            redS[w][ksub * 4 + r] = s;
            redQ[w][ksub * 4 + r] = qq;
        }
    }
    __syncthreads();

    #pragma unroll
    for (int r = 0; r < 4; ++r) {
        int rl = ksub * 4 + r;
        float sum = 0.f, sumq = 0.f;
        #pragma unroll
        for (int ww = 0; ww < 16; ++ww) {
            sum  += redS[ww][rl];
            sumq += redQ[ww][rl];
        }
        float mean = sum * (1.f / 256.f);
        float var  = sumq * (1.f / 256.f) - mean * mean;
        float rstd = rsqrtf(var + 1e-5f);
        float v = (vres[r] - mean) * rstd * g1[col] + b1t[col];
        xnf[rl * 264 + col] = v;
        sA[rl * 264 + col] = f32_to_bf16_rne(v);
    }
    __syncthreads();   // xn ready

    // ---- phase B: FFN (ff1 t=0..15, ff2 t=16..31), depth-2 rotation ----
    f32x4 acc2 = {};
    for (int t = 0; t < 32; ++t) {
        if (t < 30) {
            int tn = t + 2;
            if (tn < 16) {
                int nc = tn >> 2, kq = tn & 3;
                #pragma unroll
                for (int kk = 0; kk < 2; ++kk)
                    wn2[kk] = ldfrag(W1F, nc * 16 + w, 8, kq * 2 + kk, lane);
            } else {
                int t2 = tn - 16;
                #pragma unroll
                for (int kk = 0; kk < 2; ++kk)
                    wn2[kk] = ldfrag(W2F, w, 32, t2 * 2 + kk, lane);
            }
        }
        #pragma unroll
        for (int kk = 0; kk < 2; ++kk) {
            bf16x8 af;
            if (t < 16)
                af = *(bf16x8*)&sA[fr * 264 + (t & 3) * 64 + kk * 32 + ksub * 8];
            else
                af = *(bf16x8*)&x1s[fr * 1032 + (t - 16) * 64 + kk * 32 + ksub * 8];
            acc2 = __builtin_amdgcn_mfma_f32_16x16x32_bf16(af, wc[kk], acc2, 0, 0, 0);
        }
        if (t < 16 && (t & 3) == 3) {
            int nc = t >> 2;
            int col1 = nc * 256 + col;
            float bv = b1[col1];
            #pragma unroll
            for (int r = 0; r < 4; ++r) {
                int rl = ksub * 4 + r;
                x1s[rl * 1032 + col1] = f32_to_bf16_rne(fmaxf(acc2[r] + bv, 0.f));
            }
            acc2 = (f32x4){};
        }
        if (t == 15) __syncthreads();    // x1s complete before ff2 reads
        // rotate
        #pragma unroll
        for (int kk = 0; kk < 2; ++kk) {
            wc[kk] = wn[kk];
            wn[kk] = wn2[kk];
        }
    }

    float vres2[4];
    {
        float bv = b2[col];
        #pragma unroll
        for (int r = 0; r < 4; ++r) {
            int rl = ksub * 4 + r;
            vres2[r] = acc2[r] + bv + xnf[rl * 264 + col];
        }
    }

    #pragma unroll
    for (int r = 0; r < 4; ++r) {
        float s  = vres2[r];
        float qq = vres2[r] * vres2[r];
        #pragma unroll
        for (int mask = 1; mask < 16; mask <<= 1) {
            s  += __shfl_xor(s, mask);
            qq += __shfl_xor(qq, mask);
        }
        if (fr == 0) {
            redS[w][ksub * 4 + r] = s;
            redQ[w][ksub * 4 + r] = qq;
        }
    }
    __syncthreads();

    #pragma unroll
    for (int r = 0; r < 4; ++r) {
        int rl = ksub * 4 + r;
        float sum = 0.f, sumq = 0.f;
        #pragma unroll
        for (int ww = 0; ww < 16; ++ww) {
            sum  += redS[ww][rl];
            sumq += redQ[ww][rl];
        }
        float mean = sum * (1.f / 256.f);
        float var  = sumq * (1.f / 256.f) - mean * mean;
        float rstd = rsqrtf(var + 1e-5f);
        x[(long)(m0 + rl) * DMODEL + col] =
            (vres2[r] - mean) * rstd * g2[col] + b2t[col];
    }
}

// ===========================================================================
// Fallback (fp32) path kernels — used only if ws is too small.
// ===========================================================================
__global__ __launch_bounds__(256) void embed_kernel(
    const int* __restrict__ word_idx,
    const int* __restrict__ ngram_idx,
    const float* __restrict__ fc1_w,
    const float* __restrict__ fc1_b,
    const float* __restrict__ fc2_w,
    const float* __restrict__ fc2_b,
    float* __restrict__ x)
{
    __shared__ int   feats[8][8];
    __shared__ int   nf[8];
    __shared__ float x1[8][FFDIM];

    const int t0  = blockIdx.x * 8;
    const int tid = threadIdx.x;

    if (tid < 8) {
        int t = t0 + tid;
        int cnt = 0;
        feats[tid][cnt++] = word_idx[t];
        for (int k = 0; k < 6; ++k) {
            int f = WORDC + ngram_idx[t * 6 + k];
            bool dup = false;
            for (int s = 1; s < cnt; ++s)
                if (feats[tid][s] == f) dup = true;
            if (!dup) feats[tid][cnt++] = f;
        }
        nf[tid] = cnt;
    }
    __syncthreads();

    for (int it = 0; it < 16; ++it) {
        int item = it * 256 + tid;
        int tt = item >> 9;
        int j  = item & 511;
        float acc = fc1_b[j];
        int n = nf[tt];
        const float* rowbase = fc1_w + (long)j * F_TOT;
        for (int s = 0; s < n; ++s)
            acc += rowbase[feats[tt][s]];
        x1[tt][j] = fmaxf(acc, 0.f);
    }
    __syncthreads();

    const int d = tid;
    float acc[8];
    float bb = fc2_b[d];
    #pragma unroll
    for (int tt = 0; tt < 8; ++tt) acc[tt] = bb;
    const float* wrow = fc2_w + d * FFDIM;
    for (int k = 0; k < FFDIM; ++k) {
        float wv = wrow[k];
        #pragma unroll
        for (int tt = 0; tt < 8; ++tt) acc[tt] += wv * x1[tt][k];
    }
    #pragma unroll
    for (int tt = 0; tt < 8; ++tt)
        x[(t0 + tt) * DMODEL + d] = acc[tt];
}

template<bool RELU>
__global__ __launch_bounds__(256) void gemm_bias(
    const float* __restrict__ A,
    const float* __restrict__ W,
    const float* __restrict__ bias,
    float* __restrict__ C,
    int M, int N, int K)
{
    __shared__ float sA[16][64];
    __shared__ float sW[16][64];

    const int tid = threadIdx.x;
    const int tx = tid & 15;
    const int ty = tid >> 4;
    const int m0 = blockIdx.y * 64;
    const int n0 = blockIdx.x * 64;

    const int lr = tid >> 2;
    const int lc = tid & 3;

    float acc[4][4] = {};

    for (int k0 = 0; k0 < K; k0 += 16) {
        float4 av = *(const float4*)&A[(long)(m0 + lr) * K + k0 + lc * 4];
        float4 wv = *(const float4*)&W[(long)(n0 + lr) * K + k0 + lc * 4];
        __syncthreads();
        sA[lc * 4 + 0][lr] = av.x; sA[lc * 4 + 1][lr] = av.y;
        sA[lc * 4 + 2][lr] = av.z; sA[lc * 4 + 3][lr] = av.w;
        sW[lc * 4 + 0][lr] = wv.x; sW[lc * 4 + 1][lr] = wv.y;
        sW[lc * 4 + 2][lr] = wv.z; sW[lc * 4 + 3][lr] = wv.w;
        __syncthreads();
        #pragma unroll
        for (int k = 0; k < 16; ++k) {
            float4 a4 = *(const float4*)&sA[k][ty * 4];
            float4 b4 = *(const float4*)&sW[k][tx * 4];
            float am[4] = {a4.x, a4.y, a4.z, a4.w};
            float bn[4] = {b4.x, b4.y, b4.z, b4.w};
            #pragma unroll
            for (int i = 0; i < 4; ++i)
                #pragma unroll
                for (int j = 0; j < 4; ++j)
                    acc[i][j] += am[i] * bn[j];
        }
    }

    float4 bv = *(const float4*)&bias[n0 + tx * 4];
    #pragma unroll
    for (int i = 0; i < 4; ++i) {
        int m = m0 + ty * 4 + i;
        float4 o;
        o.x = acc[i][0] + bv.x;
        o.y = acc[i][1] + bv.y;
        o.z = acc[i][2] + bv.z;
        o.w = acc[i][3] + bv.w;
        if (RELU) {
            o.x = fmaxf(o.x, 0.f); o.y = fmaxf(o.y, 0.f);
            o.z = fmaxf(o.z, 0.f); o.w = fmaxf(o.w, 0.f);
        }
        *(float4*)&C[(long)m * N + n0 + tx * 4] = o;
    }
}

__global__ __launch_bounds__(256) void attn_kernel(
    const float* __restrict__ qkv,
    float* __restrict__ o)
{
    const int b = blockIdx.x >> 3;
    const int h = blockIdx.x & 7;
    const int tid = threadIdx.x;
    const int q = tid >> 2;
    const int p = tid & 3;

    __shared__ float Kt[SEQL][HDIM + 1];
    __shared__ float Vt[SEQL][HDIM + 1];
    __shared__ float S[SEQL][SEQL + 1];

    const float scale = 0.17677669529663687f;

    {
        int fidx = tid * 2;
        int row  = fidx >> 3;
        int c    = (fidx & 7) * 4;
        const float* kb = qkv + (long)(b * SEQL + row) * 768 + 256 + h * HDIM + c;
        float4 k0 = *(const float4*)kb;
        float4 k1 = *(const float4*)(kb + 4);
        float4 v0 = *(const float4*)(kb + 256);
        float4 v1 = *(const float4*)(kb + 260);
        *(float4*)&Kt[row][c]     = k0;
        *(float4*)&Kt[row][c + 4] = k1;
        *(float4*)&Vt[row][c]     = v0;
        *(float4*)&Vt[row][c + 4] = v1;
    }

    float qreg[HDIM];
    {
        const float* qb = qkv + (long)(b * SEQL + q) * 768 + h * HDIM;
        #pragma unroll
        for (int c = 0; c < HDIM / 4; ++c) {
            float4 v = *(const float4*)(qb + c * 4);
            qreg[c * 4 + 0] = v.x * scale;
            qreg[c * 4 + 1] = v.y * scale;
            qreg[c * 4 + 2] = v.z * scale;
            qreg[c * 4 + 3] = v.w * scale;
        }
    }
    __syncthreads();

    float sc[16];
    float mx = -1e30f;
    #pragma unroll
    for (int i = 0; i < 16; ++i) {
        int jj = p * 16 + i;
        float s = 0.f;
        #pragma unroll
        for (int d = 0; d < HDIM; ++d) s += qreg[d] * Kt[jj][d];
        sc[i] = s;
        mx = fmaxf(mx, s);
    }
    mx = fmaxf(mx, __shfl_xor(mx, 1));
    mx = fmaxf(mx, __shfl_xor(mx, 2));

    float sum = 0.f;
    #pragma unroll
    for (int i = 0; i < 16; ++i) {
        float e = __expf(sc[i] - mx);
        S[q][p * 16 + i] = e;
        sum += e;
    }
    sum += __shfl_xor(sum, 1);
    sum += __shfl_xor(sum, 2);
    const float inv = 1.f / sum;
    __syncthreads();

    float acc[8] = {};
    for (int jj = 0; jj < SEQL; ++jj) {
        float pv = S[q][jj];
        #pragma unroll
        for (int d = 0; d < 8; ++d) acc[d] += pv * Vt[jj][p * 8 + d];
    }
    float* orow = o + (long)(b * SEQL + q) * DMODEL + h * HDIM + p * 8;
    float4 o0, o1;
    o0.x = acc[0] * inv; o0.y = acc[1] * inv; o0.z = acc[2] * inv; o0.w = acc[3] * inv;
    o1.x = acc[4] * inv; o1.y = acc[5] * inv; o1.z = acc[6] * inv; o1.w = acc[7] * inv;
    *(float4*)orow = o0;
    *(float4*)(orow + 4) = o1;
}

__global__ __launch_bounds__(256) void add_ln_kernel(
    const float* __restrict__ xin,
    const float* __restrict__ f,
    const float* __restrict__ g,
    const float* __restrict__ bta,
    float* __restrict__ xout)
{
    const int w = threadIdx.x >> 6;
    const int lane = threadIdx.x & 63;
    const int t = blockIdx.x * 4 + w;

    float4 xv = *(const float4*)&xin[(long)t * DMODEL + lane * 4];
    float4 fv = *(const float4*)&f[(long)t * DMODEL + lane * 4];
    float v0 = xv.x + fv.x, v1 = xv.y + fv.y, v2 = xv.z + fv.z, v3 = xv.w + fv.w;

    float s  = v0 + v1 + v2 + v3;
    float sq = v0 * v0 + v1 * v1 + v2 * v2 + v3 * v3;
    #pragma unroll
    for (int off = 1; off < 64; off <<= 1) {
        s  += __shfl_xor(s, off);
        sq += __shfl_xor(sq, off);
    }
    float mean = s * (1.f / 256.f);
    float var  = sq * (1.f / 256.f) - mean * mean;
    float rs   = rsqrtf(var + 1e-5f);

    float4 gv = *(const float4*)&g[lane * 4];
    float4 bv = *(const float4*)&bta[lane * 4];
    float4 o;
    o.x = (v0 - mean) * rs * gv.x + bv.x;
    o.y = (v1 - mean) * rs * gv.y + bv.y;
    o.z = (v2 - mean) * rs * gv.z + bv.z;
    o.w = (v3 - mean) * rs * gv.w + bv.w;
    *(float4*)&xout[(long)t * DMODEL + lane * 4] = o;
}

// ---------------------------------------------------------------------------
extern "C" void kernel_launch(void* const* d_in, const int* in_sizes, int n_in,
                              void* d_out, int out_size, void* d_ws, size_t ws_size,
                              hipStream_t stream) {
    const int*   word_idx  = (const int*)d_in[0];
    const int*   ngram_idx = (const int*)d_in[1];
    const float* fc1_w = (const float*)d_in[2];
    const float* fc1_b = (const float*)d_in[3];
    const float* fc2_w = (const float*)d_in[4];
    const float* fc2_b = (const float*)d_in[5];
    const float* qkv_w = (const float*)d_in[6];
    const float* qkv_b = (const float*)d_in[7];
    const float* out_w = (const float*)d_in[8];
    const float* out_b = (const float*)d_in[9];
    const float* ln1_g = (const float*)d_in[10];
    const float* ln1_b = (const float*)d_in[11];
    const float* ff1_w = (const float*)d_in[12];
    const float* ff1_b = (const float*)d_in[13];
    const float* ff2_w = (const float*)d_in[14];
    const float* ff2_b = (const float*)d_in[15];
    const float* ln2_g = (const float*)d_in[16];
    const float* ln2_b = (const float*)d_in[17];

    float* x = (float*)d_out;  // [2048][256]

    const size_t BM_OFF   = 0;
    const size_t FC1T_OFF = 10240;
    const size_t FC1T_BYTES = (size_t)F_TOT * FFDIM * 2;
    const size_t QKVT_OFF = FC1T_OFF + FC1T_BYTES;
    const size_t QKVT_BYTES = (size_t)2 * 768 * 256 * 2;
    const size_t OUTT_OFF = QKVT_OFF + QKVT_BYTES;
    const size_t OUTT_BYTES = (size_t)2 * 256 * 256 * 2;
    const size_t FF1T_OFF = OUTT_OFF + OUTT_BYTES;
    const size_t FF1T_BYTES = (size_t)2 * 1024 * 256 * 2;
    const size_t FF2T_OFF = FF1T_OFF + FF1T_BYTES;
    const size_t FF2T_BYTES = (size_t)2 * 256 * 1024 * 2;
    const size_t ATTN_OFF = FF2T_OFF + FF2T_BYTES;
    const size_t ATTN_BYTES = (size_t)NTOK * DMODEL * 4;
    const size_t FAST_BYTES = ATTN_OFF + ATTN_BYTES;

    if (ws_size >= FAST_BYTES) {
        unsigned int*   bm   = (unsigned int*)((char*)d_ws + BM_OFF);
        unsigned short* fc1T = (unsigned short*)((char*)d_ws + FC1T_OFF);
        unsigned short* qkvF = (unsigned short*)((char*)d_ws + QKVT_OFF);
        unsigned short* outF = (unsigned short*)((char*)d_ws + OUTT_OFF);
        unsigned short* ff1F = (unsigned short*)((char*)d_ws + FF1T_OFF);
        unsigned short* ff2F = (unsigned short*)((char*)d_ws + FF2T_OFF);
        float* attn_raw = (float*)((char*)d_ws + ATTN_OFF);

        hipMemsetAsync((void*)bm, 0, 10240, stream);
        mark_feats_par<<<56, 256, 0, stream>>>(word_idx, ngram_idx, bm);
        transpose_cvt<<<8768, 256, 0, stream>>>(
            fc1_w, fc1T, bm, qkv_w, out_w, ff1_w, ff2_w, qkvF, outF, ff1F, ff2F);
        embed_gather<<<NTOK / 8, 256, 0, stream>>>(word_idx, ngram_idx, fc1T,
                                                   fc1_b, fc2_w, fc2_b, x);

        for (int i = 0; i < 2; ++i) {
            fused_qkv_attn<<<32 * NHEAD, 512, 0, stream>>>(
                x, qkvF + (long)i * 768 * 256, qkv_b + i * 768, attn_raw);

            outln_ffn<<<NTOK / 16, 1024, 0, stream>>>(
                attn_raw, outF + (long)i * 256 * 256, out_b + i * 256,
                ln1_g + i * 256, ln1_b + i * 256,
                ff1F + (long)i * 1024 * 256, ff1_b + i * 1024,
                ff2F + (long)i * 256 * 1024, ff2_b + i * 256,
                ln2_g + i * 256, ln2_b + i * 256, x);
        }
    } else {
        float* wsf      = (float*)d_ws;
        float* qkvbuf   = wsf;
        float* attn_raw = qkvbuf + 2048 * 768;
        float* obuf     = attn_raw + 2048 * 256;
        float* ffbuf    = obuf + 2048 * 256;

        embed_kernel<<<NTOK / 8, 256, 0, stream>>>(word_idx, ngram_idx, fc1_w,
                                                   fc1_b, fc2_w, fc2_b, x);
        for (int i = 0; i < 2; ++i) {
            gemm_bias<false><<<dim3(768 / 64, NTOK / 64), 256, 0, stream>>>(
                x, qkv_w + (long)i * 768 * 256, qkv_b + i * 768, qkvbuf,
                NTOK, 768, 256);
            attn_kernel<<<32 * NHEAD, 256, 0, stream>>>(qkvbuf, attn_raw);
            gemm_bias<false><<<dim3(256 / 64, NTOK / 64), 256, 0, stream>>>(
                attn_raw, out_w + (long)i * 256 * 256, out_b + i * 256, obuf,
                NTOK, 256, 256);
            add_ln_kernel<<<NTOK / 4, 256, 0, stream>>>(x, obuf, ln1_g + i * 256,
                                                        ln1_b + i * 256, x);
            gemm_bias<true><<<dim3(1024 / 64, NTOK / 64), 256, 0, stream>>>(
                x, ff1_w + (long)i * 1024 * 256, ff1_b + i * 1024, ffbuf,
                NTOK, 1024, 256);
            gemm_bias<false><<<dim3(256 / 64, NTOK / 64), 256, 0, stream>>>(
                ffbuf, ff2_w + (long)i * 256 * 1024, ff2_b + i * 256, obuf,
                NTOK, 256, 1024);
            add_ln_kernel<<<NTOK / 4, 256, 0, stream>>>(x, obuf, ln2_g + i * 256,
                                                        ln2_b + i * 256, x);
        }
    }
}

// Round 21
// 118.319 us; speedup vs baseline: 1.0633x; 1.0633x over previous
//
#include <hip/hip_runtime.h>
#include <hip/hip_bf16.h>
#include <math.h>

#define WORDC 30000
#define F_TOT 80000
#define NTOK  2048
#define DMODEL 256
#define FFDIM 512
#define NHEAD 8
#define HDIM  32
#define SEQL  64

typedef __attribute__((ext_vector_type(8))) short bf16x8;
typedef __attribute__((ext_vector_type(8))) unsigned short u16x8;
typedef __attribute__((ext_vector_type(4))) float f32x4;

__device__ __forceinline__ unsigned short f32_to_bf16_rne(float x) {
    unsigned int u = __float_as_uint(x);
    unsigned int r = (u + 0x7FFFu + ((u >> 16) & 1u)) >> 16;
    return (unsigned short)r;
}

__device__ __forceinline__ u16x8 cvt8(float4 a, float4 b) {
    u16x8 v;
    v[0] = f32_to_bf16_rne(a.x); v[1] = f32_to_bf16_rne(a.y);
    v[2] = f32_to_bf16_rne(a.z); v[3] = f32_to_bf16_rne(a.w);
    v[4] = f32_to_bf16_rne(b.x); v[5] = f32_to_bf16_rne(b.y);
    v[6] = f32_to_bf16_rne(b.z); v[7] = f32_to_bf16_rne(b.w);
    return v;
}

// load one MFMA B-fragment from fragment-major packed weights:
// layout elems[((ntile*KT + ktile)*64 + lane)*8], row = ntile*16+(lane&15),
// k = ktile*32+(lane>>4)*8.
__device__ __forceinline__ bf16x8 ldfrag(const unsigned short* F, int ntile,
                                          int KT, int ktile, int lane) {
    return *(const bf16x8*)&F[(((long)(ntile * KT + ktile) * 64 + lane) << 3)];
}

// ---------------------------------------------------------------------------
// Parallel bitmap mark. Grid 56; bm zeroed via hipMemsetAsync first.
// ---------------------------------------------------------------------------
__global__ __launch_bounds__(256) void mark_feats_par(
    const int* __restrict__ word_idx,
    const int* __restrict__ ngram_idx,
    unsigned int* __restrict__ bm)
{
    int i = blockIdx.x * 256 + threadIdx.x;
    int f;
    if (i < NTOK)                f = word_idx[i];
    else if (i < NTOK * 7)       f = WORDC + ngram_idx[i - NTOK];
    else                         return;
    atomicOr(&bm[f >> 5], 1u << (f & 31));
}

// ---------------------------------------------------------------------------
// Transpose fc1_w (store-pruned) + repack transformer weights into
// fragment-major bf16. Grid: [0,8000) transpose, [8000,8768) repack.
// ---------------------------------------------------------------------------
__global__ __launch_bounds__(256) void transpose_cvt(
    const float* __restrict__ fc1_w,
    unsigned short* __restrict__ fc1T,
    const unsigned int* __restrict__ bm,
    const float* __restrict__ s0, const float* __restrict__ s1,
    const float* __restrict__ s2, const float* __restrict__ s3,
    unsigned short* __restrict__ d0, unsigned short* __restrict__ d1,
    unsigned short* __restrict__ d2, unsigned short* __restrict__ d3)
{
    __shared__ float tile[320][17];
    const int bid = blockIdx.x;
    const int tid = threadIdx.x;

    if (bid < 8000) {
        const int f0 = (bid % 250) * 320;
        const int j0 = (bid / 250) * 16;

        #pragma unroll
        for (int it = 0; it < 5; ++it) {
            int idx = it * 256 + tid;
            int jr  = idx / 80;
            int c4  = idx - jr * 80;
            float4 v = *(const float4*)&fc1_w[(long)(j0 + jr) * F_TOT + f0 + c4 * 4];
            tile[c4 * 4 + 0][jr] = v.x;
            tile[c4 * 4 + 1][jr] = v.y;
            tile[c4 * 4 + 2][jr] = v.z;
            tile[c4 * 4 + 3][jr] = v.w;
        }
        __syncthreads();

        for (int f = tid; f < 320; f += 256) {
            int fg = f0 + f;
            if ((bm[fg >> 5] >> (fg & 31)) & 1u) {
                u16x8 lo, hi;
                #pragma unroll
                for (int j = 0; j < 8; ++j) {
                    lo[j] = f32_to_bf16_rne(tile[f][j]);
                    hi[j] = f32_to_bf16_rne(tile[f][j + 8]);
                }
                *(u16x8*)&fc1T[(long)fg * FFDIM + j0]     = lo;
                *(u16x8*)&fc1T[(long)fg * FFDIM + j0 + 8] = hi;
            }
        }
    } else {
        // fragment-major repack: one fragment (8 elems) per thread.
        // tensor frag counts: qkv 49152 | out 16384 | ff1 65536 | ff2 65536
        long fid = (long)(bid - 8000) * 256 + tid;   // 0..196607
        const float* src; unsigned short* dst; int K; long base;
        if (fid < 49152)        { src = s0; dst = d0; K = 256;  base = fid; }
        else if (fid < 65536)   { src = s1; dst = d1; K = 256;  base = fid - 49152; }
        else if (fid < 131072)  { src = s2; dst = d2; K = 256;  base = fid - 65536; }
        else                    { src = s3; dst = d3; K = 1024; base = fid - 131072; }
        int lane = (int)(base & 63);
        long t   = base >> 6;
        int KT   = K >> 5;
        int ntile = (int)(t / KT);
        int ktile = (int)(t - (long)ntile * KT);
        int row = ntile * 16 + (lane & 15);
        int k   = ktile * 32 + (lane >> 4) * 8;
        const float* sp = src + (long)row * K + k;
        u16x8 v;
        #pragma unroll
        for (int j = 0; j < 8; ++j) v[j] = f32_to_bf16_rne(sp[j]);
        *(u16x8*)&dst[base << 3] = v;
    }
}

// ---------------------------------------------------------------------------
// Gather: fixed-trip masked 7-feat sum -> relu -> fc2. (R14 proven)
// ---------------------------------------------------------------------------
__global__ __launch_bounds__(256) void embed_gather(
    const int* __restrict__ word_idx,
    const int* __restrict__ ngram_idx,
    const unsigned short* __restrict__ fc1_wT,
    const float* __restrict__ fc1_b,
    const float* __restrict__ fc2_w,
    const float* __restrict__ fc2_b,
    float* __restrict__ x)
{
    __shared__ int   feats[8][8];
    __shared__ float wmsk[8][8];
    __shared__ float x1[8][FFDIM];

    const int t0  = blockIdx.x * 8;
    const int tid = threadIdx.x;

    if (tid < 8) {
        int t = t0 + tid;
        feats[tid][0] = word_idx[t];
        wmsk[tid][0]  = 1.f;
        #pragma unroll
        for (int k = 0; k < 6; ++k) {
            int f = WORDC + ngram_idx[t * 6 + k];
            bool dup = false;
            for (int s = 1; s <= k; ++s)
                if (feats[tid][s] == f) dup = true;
            feats[tid][1 + k] = f;
            wmsk[tid][1 + k]  = dup ? 0.f : 1.f;
        }
    }
    __syncthreads();

    const float2 bb = *(const float2*)&fc1_b[tid * 2];
    #pragma unroll
    for (int tt = 0; tt < 8; ++tt) {
        float a0 = bb.x, a1 = bb.y;
        #pragma unroll
        for (int s = 0; s < 7; ++s) {
            unsigned int wrd = *(const unsigned int*)
                &fc1_wT[(long)feats[tt][s] * FFDIM + tid * 2];
            float m = wmsk[tt][s];
            a0 += m * __uint_as_float((wrd & 0xFFFFu) << 16);
            a1 += m * __uint_as_float(wrd & 0xFFFF0000u);
        }
        x1[tt][tid * 2 + 0] = fmaxf(a0, 0.f);
        x1[tt][tid * 2 + 1] = fmaxf(a1, 0.f);
    }
    __syncthreads();

    const int d = tid;
    float acc[8];
    float cb = fc2_b[d];
    #pragma unroll
    for (int tt = 0; tt < 8; ++tt) acc[tt] = cb;
    const float* wrow = fc2_w + d * FFDIM;
    for (int k = 0; k < FFDIM; ++k) {
        float wv = wrow[k];
        #pragma unroll
        for (int tt = 0; tt < 8; ++tt) acc[tt] += wv * x1[tt][k];
    }
    #pragma unroll
    for (int tt = 0; tt < 8; ++tt)
        x[(t0 + tt) * DMODEL + d] = acc[tt];
}

// ---------------------------------------------------------------------------
// Fused per-(b,h) QKV GEMM + MFMA attention. W direct fragment loads.
// (R18 proven, ~2.5us/dispatch)
// ---------------------------------------------------------------------------
__global__ __launch_bounds__(512, 4) void fused_qkv_attn(
    const float* __restrict__ x,
    const unsigned short* __restrict__ WqF,  // layer qkv frag-packed [768][256]
    const float* __restrict__ bq,
    float* __restrict__ o)
{
    __shared__ unsigned short sA[64 * 264];
    __shared__ unsigned short sQ[64 * 40];
    __shared__ unsigned short sK[64 * 40];
    __shared__ unsigned short sVt[32 * 72];
    __shared__ unsigned short sP[64 * 72];
    __shared__ float sfmx[2][64];
    __shared__ float sfsm[2][64];

    const int b = blockIdx.x >> 3;
    const int h = blockIdx.x & 7;
    const int tid  = threadIdx.x;
    const int lane = tid & 63;
    const int w    = tid >> 6;          // 0..7
    const int rg   = w & 3;             // query-row group
    const int ch   = w >> 2;            // col half
    const int fr   = lane & 15;
    const int ksub = lane >> 4;
    const int row0 = b * SEQL;

    int nt[3];
    #pragma unroll
    for (int ni = 0; ni < 3; ++ni) {
        int c = ch * 48 + ni * 16;
        int part = c >> 5, pcb = c & 31;
        nt[ni] = (part * 256 + h * HDIM + pcb) >> 4;
    }

    #pragma unroll
    for (int j = 0; j < 4; ++j) {
        int c = j * 512 + tid;
        int row = c >> 5, c8 = c & 31;
        const float* ap = &x[(long)(row0 + row) * DMODEL + c8 * 8];
        float4 a0 = *(const float4*)ap;
        float4 a1 = *(const float4*)(ap + 4);
        *(u16x8*)&sA[row * 264 + c8 * 8] = cvt8(a0, a1);
    }

    bf16x8 wf[2][2][3];
    #pragma unroll
    for (int kk = 0; kk < 2; ++kk)
        #pragma unroll
        for (int ni = 0; ni < 3; ++ni)
            wf[0][kk][ni] = ldfrag(WqF, nt[ni], 8, kk, lane);
    #pragma unroll
    for (int kk = 0; kk < 2; ++kk)
        #pragma unroll
        for (int ni = 0; ni < 3; ++ni)
            wf[1][kk][ni] = ldfrag(WqF, nt[ni], 8, 2 + kk, lane);

    __syncthreads();   // sA ready

    f32x4 acc[3] = {};
    #pragma unroll
    for (int t = 0; t < 4; ++t) {
        const int cur = t & 1;
        #pragma unroll
        for (int kk = 0; kk < 2; ++kk) {
            bf16x8 af = *(bf16x8*)&sA[(rg * 16 + fr) * 264 + t * 64 + kk * 32 + ksub * 8];
            #pragma unroll
            for (int ni = 0; ni < 3; ++ni)
                acc[ni] = __builtin_amdgcn_mfma_f32_16x16x32_bf16(af, wf[cur][kk][ni], acc[ni], 0, 0, 0);
        }
        if (t + 2 < 4) {
            #pragma unroll
            for (int kk = 0; kk < 2; ++kk)
                #pragma unroll
                for (int ni = 0; ni < 3; ++ni)
                    wf[cur][kk][ni] = ldfrag(WqF, nt[ni], 8, (t + 2) * 2 + kk, lane);
        }
    }

    const float scale = 0.17677669529663687f;   // 1/sqrt(32)
    #pragma unroll
    for (int ni = 0; ni < 3; ++ni) {
        int c = ch * 48 + ni * 16 + fr;
        int part = c >> 5, pc = c & 31;
        float bv = bq[part * 256 + h * HDIM + pc];
        #pragma unroll
        for (int r = 0; r < 4; ++r) {
            int row = rg * 16 + ksub * 4 + r;
            float v = acc[ni][r] + bv;
            if (part == 0)      sQ[row * 40 + pc] = f32_to_bf16_rne(v * scale);
            else if (part == 1) sK[row * 40 + pc] = f32_to_bf16_rne(v);
            else                sVt[pc * 72 + row] = f32_to_bf16_rne(v);
        }
    }
    __syncthreads();

    f32x4 s4[2];
    {
        bf16x8 afq = *(bf16x8*)&sQ[(rg * 16 + fr) * 40 + ksub * 8];
        #pragma unroll
        for (int ni = 0; ni < 2; ++ni) {
            bf16x8 bfk = *(bf16x8*)&sK[(ch * 32 + ni * 16 + fr) * 40 + ksub * 8];
            f32x4 z = {};
            s4[ni] = __builtin_amdgcn_mfma_f32_16x16x32_bf16(afq, bfk, z, 0, 0, 0);
        }
    }

    #pragma unroll
    for (int r = 0; r < 4; ++r) {
        float m = fmaxf(s4[0][r], s4[1][r]);
        m = fmaxf(m, __shfl_xor(m, 1));
        m = fmaxf(m, __shfl_xor(m, 2));
        m = fmaxf(m, __shfl_xor(m, 4));
        m = fmaxf(m, __shfl_xor(m, 8));
        if (fr == 0) sfmx[ch][rg * 16 + ksub * 4 + r] = m;
    }
    __syncthreads();
    float minv[4];
    #pragma unroll
    for (int r = 0; r < 4; ++r) {
        int row = rg * 16 + ksub * 4 + r;
        float m = fmaxf(sfmx[0][row], sfmx[1][row]);
        float p0 = __expf(s4[0][r] - m);
        float p1 = __expf(s4[1][r] - m);
        sP[row * 72 + ch * 32 + fr]      = f32_to_bf16_rne(p0);
        sP[row * 72 + ch * 32 + 16 + fr] = f32_to_bf16_rne(p1);
        float s = p0 + p1;
        s += __shfl_xor(s, 1);
        s += __shfl_xor(s, 2);
        s += __shfl_xor(s, 4);
        s += __shfl_xor(s, 8);
        if (fr == 0) sfsm[ch][row] = s;
    }
    __syncthreads();
    #pragma unroll
    for (int r = 0; r < 4; ++r) {
        int row = rg * 16 + ksub * 4 + r;
        minv[r] = 1.f / (sfsm[0][row] + sfsm[1][row]);
    }

    f32x4 o4 = {};
    #pragma unroll
    for (int kc = 0; kc < 2; ++kc) {
        bf16x8 afp = *(bf16x8*)&sP[(rg * 16 + fr) * 72 + kc * 32 + ksub * 8];
        bf16x8 bfv = *(bf16x8*)&sVt[(ch * 16 + fr) * 72 + kc * 32 + ksub * 8];
        o4 = __builtin_amdgcn_mfma_f32_16x16x32_bf16(afp, bfv, o4, 0, 0, 0);
    }
    #pragma unroll
    for (int r = 0; r < 4; ++r) {
        int row = row0 + rg * 16 + ksub * 4 + r;
        o[(long)row * DMODEL + h * HDIM + ch * 16 + fr] = o4[r] * minv[r];
    }
}

// ---------------------------------------------------------------------------
// Fused out-proj + LN1 + FFN + LN2, BM=16 rows (all MFMA rows real).
// grid 128, 512 thr. W direct fragment loads. (R19 proven best)
// ---------------------------------------------------------------------------
__global__ __launch_bounds__(512, 4) void outln_ffn(
    const float* __restrict__ attn_raw,
    const unsigned short* __restrict__ WoF,  // frag-packed [256][256]
    const float* __restrict__ bo,
    const float* __restrict__ g1, const float* __restrict__ b1t,
    const unsigned short* __restrict__ W1F,  // frag-packed [1024][256]
    const float* __restrict__ b1,
    const unsigned short* __restrict__ W2F,  // frag-packed [256][1024]
    const float* __restrict__ b2,
    const float* __restrict__ g2, const float* __restrict__ b2t,
    float* __restrict__ x)                   // residual in, final out
{
    __shared__ unsigned short sA[16 * 264];
    __shared__ float xnf[16 * 264];
    __shared__ unsigned short x1s[16 * 1032];
    __shared__ float redS[8][16];
    __shared__ float redQ[8][16];

    const int tid  = threadIdx.x;
    const int lane = tid & 63;
    const int w    = tid >> 6;
    const int fr   = lane & 15;
    const int ksub = lane >> 4;
    const int m0   = blockIdx.x * 16;

    // stage attn_raw rows 0..15 (bf16): 512 chunks, one per thread
    {
        int row = tid >> 5, c8 = tid & 31;
        const float* ap = &attn_raw[(long)(m0 + row) * DMODEL + c8 * 8];
        float4 a0 = *(const float4*)ap;
        float4 a1 = *(const float4*)(ap + 4);
        *(u16x8*)&sA[row * 264 + c8 * 8] = cvt8(a0, a1);
    }

    // depth-2 Wo fragment prefetch (t=0,1)
    bf16x8 wf[2][2][2];
    #pragma unroll
    for (int kk = 0; kk < 2; ++kk)
        #pragma unroll
        for (int ni = 0; ni < 2; ++ni)
            wf[0][kk][ni] = ldfrag(WoF, w * 2 + ni, 8, kk, lane);
    #pragma unroll
    for (int kk = 0; kk < 2; ++kk)
        #pragma unroll
        for (int ni = 0; ni < 2; ++ni)
            wf[1][kk][ni] = ldfrag(WoF, w * 2 + ni, 8, 2 + kk, lane);

    __syncthreads();

    // ---- phase A: out-projection ----
    f32x4 acc[2] = {};
    #pragma unroll
    for (int t = 0; t < 4; ++t) {
        const int cur = t & 1;
        #pragma unroll
        for (int kk = 0; kk < 2; ++kk) {
            bf16x8 af = *(bf16x8*)&sA[fr * 264 + t * 64 + kk * 32 + ksub * 8];
            #pragma unroll
            for (int ni = 0; ni < 2; ++ni)
                acc[ni] = __builtin_amdgcn_mfma_f32_16x16x32_bf16(af, wf[cur][kk][ni], acc[ni], 0, 0, 0);
        }
        if (t + 2 < 4) {
            #pragma unroll
            for (int kk = 0; kk < 2; ++kk)
                #pragma unroll
                for (int ni = 0; ni < 2; ++ni)
                    wf[cur][kk][ni] = ldfrag(WoF, w * 2 + ni, 8, (t + 2) * 2 + kk, lane);
        }
    }

    float vres[2][4];
    #pragma unroll
    for (int ni = 0; ni < 2; ++ni) {
        int col = w * 32 + ni * 16 + fr;
        float bv = bo[col];
        #pragma unroll
        for (int r = 0; r < 4; ++r) {
            int rl = ksub * 4 + r;
            vres[ni][r] = acc[ni][r] + bv + x[(long)(m0 + rl) * DMODEL + col];
        }
    }

    // prefetch W1 t=0,1 while LN reduces
    bf16x8 wc[2][2], wn[2][2], wn2[2][2];
    #pragma unroll
    for (int kk = 0; kk < 2; ++kk)
        #pragma unroll
        for (int ni = 0; ni < 2; ++ni) {
            wc[kk][ni] = ldfrag(W1F, w * 2 + ni, 8, kk, lane);
            wn[kk][ni] = ldfrag(W1F, w * 2 + ni, 8, 2 + kk, lane);
        }

    #pragma unroll
    for (int r = 0; r < 4; ++r) {
        float s  = vres[0][r] + vres[1][r];
        float qq = vres[0][r] * vres[0][r] + vres[1][r] * vres[1][r];
        #pragma unroll
        for (int mask = 1; mask < 16; mask <<= 1) {
            s  += __shfl_xor(s, mask);
            qq += __shfl_xor(qq, mask);
        }
        if (fr == 0) {
            redS[w][ksub * 4 + r] = s;
            redQ[w][ksub * 4 + r] = qq;
        }
    }
    __syncthreads();

    #pragma unroll
    for (int r = 0; r < 4; ++r) {
        int rl = ksub * 4 + r;
        float sum = 0.f, sumq = 0.f;
        #pragma unroll
        for (int ww = 0; ww < 8; ++ww) {
            sum  += redS[ww][rl];
            sumq += redQ[ww][rl];
        }
        float mean = sum * (1.f / 256.f);
        float var  = sumq * (1.f / 256.f) - mean * mean;
        float rstd = rsqrtf(var + 1e-5f);
        #pragma unroll
        for (int ni = 0; ni < 2; ++ni) {
            int col = w * 32 + ni * 16 + fr;
            float v = (vres[ni][r] - mean) * rstd * g1[col] + b1t[col];
            xnf[rl * 264 + col] = v;
            sA[rl * 264 + col] = f32_to_bf16_rne(v);
        }
    }
    __syncthreads();   // xn ready

    // ---- phase B: FFN (ff1 t=0..15, ff2 t=16..31), depth-2 rotation ----
    f32x4 acc2[2] = {};
    for (int t = 0; t < 32; ++t) {
        if (t < 30) {
            int tn = t + 2;
            if (tn < 16) {
                int nc = tn >> 2, kq = tn & 3;
                #pragma unroll
                for (int kk = 0; kk < 2; ++kk)
                    #pragma unroll
                    for (int ni = 0; ni < 2; ++ni)
                        wn2[kk][ni] = ldfrag(W1F, nc * 16 + w * 2 + ni, 8, kq * 2 + kk, lane);
            } else {
                int t2 = tn - 16;
                #pragma unroll
                for (int kk = 0; kk < 2; ++kk)
                    #pragma unroll
                    for (int ni = 0; ni < 2; ++ni)
                        wn2[kk][ni] = ldfrag(W2F, w * 2 + ni, 32, t2 * 2 + kk, lane);
            }
        }
        #pragma unroll
        for (int kk = 0; kk < 2; ++kk) {
            bf16x8 af;
            if (t < 16)
                af = *(bf16x8*)&sA[fr * 264 + (t & 3) * 64 + kk * 32 + ksub * 8];
            else
                af = *(bf16x8*)&x1s[fr * 1032 + (t - 16) * 64 + kk * 32 + ksub * 8];
            #pragma unroll
            for (int ni = 0; ni < 2; ++ni)
                acc2[ni] = __builtin_amdgcn_mfma_f32_16x16x32_bf16(af, wc[kk][ni], acc2[ni], 0, 0, 0);
        }
        if (t < 16 && (t & 3) == 3) {
            int nc = t >> 2;
            #pragma unroll
            for (int ni = 0; ni < 2; ++ni) {
                int col = nc * 256 + w * 32 + ni * 16 + fr;
                float bv = b1[col];
                #pragma unroll
                for (int r = 0; r < 4; ++r) {
                    int rl = ksub * 4 + r;
                    x1s[rl * 1032 + col] = f32_to_bf16_rne(fmaxf(acc2[ni][r] + bv, 0.f));
                }
                acc2[ni] = (f32x4){};
            }
        }
        if (t == 15) __syncthreads();    // x1s complete before ff2 reads
        // rotate
        #pragma unroll
        for (int kk = 0; kk < 2; ++kk)
            #pragma unroll
            for (int ni = 0; ni < 2; ++ni) {
                wc[kk][ni] = wn[kk][ni];
                wn[kk][ni] = wn2[kk][ni];
            }
    }

    float vres2[2][4];
    #pragma unroll
    for (int ni = 0; ni < 2; ++ni) {
        int col = w * 32 + ni * 16 + fr;
        float bv = b2[col];
        #pragma unroll
        for (int r = 0; r < 4; ++r) {
            int rl = ksub * 4 + r;
            vres2[ni][r] = acc2[ni][r] + bv + xnf[rl * 264 + col];
        }
    }

    #pragma unroll
    for (int r = 0; r < 4; ++r) {
        float s  = vres2[0][r] + vres2[1][r];
        float qq = vres2[0][r] * vres2[0][r] + vres2[1][r] * vres2[1][r];
        #pragma unroll
        for (int mask = 1; mask < 16; mask <<= 1) {
            s  += __shfl_xor(s, mask);
            qq += __shfl_xor(qq, mask);
        }
        if (fr == 0) {
            redS[w][ksub * 4 + r] = s;
            redQ[w][ksub * 4 + r] = qq;
        }
    }
    __syncthreads();

    #pragma unroll
    for (int r = 0; r < 4; ++r) {
        int rl = ksub * 4 + r;
        float sum = 0.f, sumq = 0.f;
        #pragma unroll
        for (int ww = 0; ww < 8; ++ww) {
            sum  += redS[ww][rl];
            sumq += redQ[ww][rl];
        }
        float mean = sum * (1.f / 256.f);
        float var  = sumq * (1.f / 256.f) - mean * mean;
        float rstd = rsqrtf(var + 1e-5f);
        #pragma unroll
        for (int ni = 0; ni < 2; ++ni) {
            int col = w * 32 + ni * 16 + fr;
            x[(long)(m0 + rl) * DMODEL + col] =
                (vres2[ni][r] - mean) * rstd * g2[col] + b2t[col];
        }
    }
}

// ===========================================================================
// Fallback (fp32) path kernels — used only if ws is too small.
// ===========================================================================
__global__ __launch_bounds__(256) void embed_kernel(
    const int* __restrict__ word_idx,
    const int* __restrict__ ngram_idx,
    const float* __restrict__ fc1_w,
    const float* __restrict__ fc1_b,
    const float* __restrict__ fc2_w,
    const float* __restrict__ fc2_b,
    float* __restrict__ x)
{
    __shared__ int   feats[8][8];
    __shared__ int   nf[8];
    __shared__ float x1[8][FFDIM];

    const int t0  = blockIdx.x * 8;
    const int tid = threadIdx.x;

    if (tid < 8) {
        int t = t0 + tid;
        int cnt = 0;
        feats[tid][cnt++] = word_idx[t];
        for (int k = 0; k < 6; ++k) {
            int f = WORDC + ngram_idx[t * 6 + k];
            bool dup = false;
            for (int s = 1; s < cnt; ++s)
                if (feats[tid][s] == f) dup = true;
            if (!dup) feats[tid][cnt++] = f;
        }
        nf[tid] = cnt;
    }
    __syncthreads();

    for (int it = 0; it < 16; ++it) {
        int item = it * 256 + tid;
        int tt = item >> 9;
        int j  = item & 511;
        float acc = fc1_b[j];
        int n = nf[tt];
        const float* rowbase = fc1_w + (long)j * F_TOT;
        for (int s = 0; s < n; ++s)
            acc += rowbase[feats[tt][s]];
        x1[tt][j] = fmaxf(acc, 0.f);
    }
    __syncthreads();

    const int d = tid;
    float acc[8];
    float bb = fc2_b[d];
    #pragma unroll
    for (int tt = 0; tt < 8; ++tt) acc[tt] = bb;
    const float* wrow = fc2_w + d * FFDIM;
    for (int k = 0; k < FFDIM; ++k) {
        float wv = wrow[k];
        #pragma unroll
        for (int tt = 0; tt < 8; ++tt) acc[tt] += wv * x1[tt][k];
    }
    #pragma unroll
    for (int tt = 0; tt < 8; ++tt)
        x[(t0 + tt) * DMODEL + d] = acc[tt];
}

template<bool RELU>
__global__ __launch_bounds__(256) void gemm_bias(
    const float* __restrict__ A,
    const float* __restrict__ W,
    const float* __restrict__ bias,
    float* __restrict__ C,
    int M, int N, int K)
{
    __shared__ float sA[16][64];
    __shared__ float sW[16][64];

    const int tid = threadIdx.x;
    const int tx = tid & 15;
    const int ty = tid >> 4;
    const int m0 = blockIdx.y * 64;
    const int n0 = blockIdx.x * 64;

    const int lr = tid >> 2;
    const int lc = tid & 3;

    float acc[4][4] = {};

    for (int k0 = 0; k0 < K; k0 += 16) {
        float4 av = *(const float4*)&A[(long)(m0 + lr) * K + k0 + lc * 4];
        float4 wv = *(const float4*)&W[(long)(n0 + lr) * K + k0 + lc * 4];
        __syncthreads();
        sA[lc * 4 + 0][lr] = av.x; sA[lc * 4 + 1][lr] = av.y;
        sA[lc * 4 + 2][lr] = av.z; sA[lc * 4 + 3][lr] = av.w;
        sW[lc * 4 + 0][lr] = wv.x; sW[lc * 4 + 1][lr] = wv.y;
        sW[lc * 4 + 2][lr] = wv.z; sW[lc * 4 + 3][lr] = wv.w;
        __syncthreads();
        #pragma unroll
        for (int k = 0; k < 16; ++k) {
            float4 a4 = *(const float4*)&sA[k][ty * 4];
            float4 b4 = *(const float4*)&sW[k][tx * 4];
            float am[4] = {a4.x, a4.y, a4.z, a4.w};
            float bn[4] = {b4.x, b4.y, b4.z, b4.w};
            #pragma unroll
            for (int i = 0; i < 4; ++i)
                #pragma unroll
                for (int j = 0; j < 4; ++j)
                    acc[i][j] += am[i] * bn[j];
        }
    }

    float4 bv = *(const float4*)&bias[n0 + tx * 4];
    #pragma unroll
    for (int i = 0; i < 4; ++i) {
        int m = m0 + ty * 4 + i;
        float4 o;
        o.x = acc[i][0] + bv.x;
        o.y = acc[i][1] + bv.y;
        o.z = acc[i][2] + bv.z;
        o.w = acc[i][3] + bv.w;
        if (RELU) {
            o.x = fmaxf(o.x, 0.f); o.y = fmaxf(o.y, 0.f);
            o.z = fmaxf(o.z, 0.f); o.w = fmaxf(o.w, 0.f);
        }
        *(float4*)&C[(long)m * N + n0 + tx * 4] = o;
    }
}

__global__ __launch_bounds__(256) void attn_kernel(
    const float* __restrict__ qkv,
    float* __restrict__ o)
{
    const int b = blockIdx.x >> 3;
    const int h = blockIdx.x & 7;
    const int tid = threadIdx.x;
    const int q = tid >> 2;
    const int p = tid & 3;

    __shared__ float Kt[SEQL][HDIM + 1];
    __shared__ float Vt[SEQL][HDIM + 1];
    __shared__ float S[SEQL][SEQL + 1];

    const float scale = 0.17677669529663687f;

    {
        int fidx = tid * 2;
        int row  = fidx >> 3;
        int c    = (fidx & 7) * 4;
        const float* kb = qkv + (long)(b * SEQL + row) * 768 + 256 + h * HDIM + c;
        float4 k0 = *(const float4*)kb;
        float4 k1 = *(const float4*)(kb + 4);
        float4 v0 = *(const float4*)(kb + 256);
        float4 v1 = *(const float4*)(kb + 260);
        *(float4*)&Kt[row][c]     = k0;
        *(float4*)&Kt[row][c + 4] = k1;
        *(float4*)&Vt[row][c]     = v0;
        *(float4*)&Vt[row][c + 4] = v1;
    }

    float qreg[HDIM];
    {
        const float* qb = qkv + (long)(b * SEQL + q) * 768 + h * HDIM;
        #pragma unroll
        for (int c = 0; c < HDIM / 4; ++c) {
            float4 v = *(const float4*)(qb + c * 4);
            qreg[c * 4 + 0] = v.x * scale;
            qreg[c * 4 + 1] = v.y * scale;
            qreg[c * 4 + 2] = v.z * scale;
            qreg[c * 4 + 3] = v.w * scale;
        }
    }
    __syncthreads();

    float sc[16];
    float mx = -1e30f;
    #pragma unroll
    for (int i = 0; i < 16; ++i) {
        int jj = p * 16 + i;
        float s = 0.f;
        #pragma unroll
        for (int d = 0; d < HDIM; ++d) s += qreg[d] * Kt[jj][d];
        sc[i] = s;
        mx = fmaxf(mx, s);
    }
    mx = fmaxf(mx, __shfl_xor(mx, 1));
    mx = fmaxf(mx, __shfl_xor(mx, 2));

    float sum = 0.f;
    #pragma unroll
    for (int i = 0; i < 16; ++i) {
        float e = __expf(sc[i] - mx);
        S[q][p * 16 + i] = e;
        sum += e;
    }
    sum += __shfl_xor(sum, 1);
    sum += __shfl_xor(sum, 2);
    const float inv = 1.f / sum;
    __syncthreads();

    float acc[8] = {};
    for (int jj = 0; jj < SEQL; ++jj) {
        float pv = S[q][jj];
        #pragma unroll
        for (int d = 0; d < 8; ++d) acc[d] += pv * Vt[jj][p * 8 + d];
    }
    float* orow = o + (long)(b * SEQL + q) * DMODEL + h * HDIM + p * 8;
    float4 o0, o1;
    o0.x = acc[0] * inv; o0.y = acc[1] * inv; o0.z = acc[2] * inv; o0.w = acc[3] * inv;
    o1.x = acc[4] * inv; o1.y = acc[5] * inv; o1.z = acc[6] * inv; o1.w = acc[7] * inv;
    *(float4*)orow = o0;
    *(float4*)(orow + 4) = o1;
}

__global__ __launch_bounds__(256) void add_ln_kernel(
    const float* __restrict__ xin,
    const float* __restrict__ f,
    const float* __restrict__ g,
    const float* __restrict__ bta,
    float* __restrict__ xout)
{
    const int w = threadIdx.x >> 6;
    const int lane = threadIdx.x & 63;
    const int t = blockIdx.x * 4 + w;

    float4 xv = *(const float4*)&xin[(long)t * DMODEL + lane * 4];
    float4 fv = *(const float4*)&f[(long)t * DMODEL + lane * 4];
    float v0 = xv.x + fv.x, v1 = xv.y + fv.y, v2 = xv.z + fv.z, v3 = xv.w + fv.w;

    float s  = v0 + v1 + v2 + v3;
    float sq = v0 * v0 + v1 * v1 + v2 * v2 + v3 * v3;
    #pragma unroll
    for (int off = 1; off < 64; off <<= 1) {
        s  += __shfl_xor(s, off);
        sq += __shfl_xor(sq, off);
    }
    float mean = s * (1.f / 256.f);
    float var  = sq * (1.f / 256.f) - mean * mean;
    float rs   = rsqrtf(var + 1e-5f);

    float4 gv = *(const float4*)&g[lane * 4];
    float4 bv = *(const float4*)&bta[lane * 4];
    float4 o;
    o.x = (v0 - mean) * rs * gv.x + bv.x;
    o.y = (v1 - mean) * rs * gv.y + bv.y;
    o.z = (v2 - mean) * rs * gv.z + bv.z;
    o.w = (v3 - mean) * rs * gv.w + bv.w;
    *(float4*)&xout[(long)t * DMODEL + lane * 4] = o;
}

// ---------------------------------------------------------------------------
extern "C" void kernel_launch(void* const* d_in, const int* in_sizes, int n_in,
                              void* d_out, int out_size, void* d_ws, size_t ws_size,
                              hipStream_t stream) {
    const int*   word_idx  = (const int*)d_in[0];
    const int*   ngram_idx = (const int*)d_in[1];
    const float* fc1_w = (const float*)d_in[2];
    const float* fc1_b = (const float*)d_in[3];
    const float* fc2_w = (const float*)d_in[4];
    const float* fc2_b = (const float*)d_in[5];
    const float* qkv_w = (const float*)d_in[6];
    const float* qkv_b = (const float*)d_in[7];
    const float* out_w = (const float*)d_in[8];
    const float* out_b = (const float*)d_in[9];
    const float* ln1_g = (const float*)d_in[10];
    const float* ln1_b = (const float*)d_in[11];
    const float* ff1_w = (const float*)d_in[12];
    const float* ff1_b = (const float*)d_in[13];
    const float* ff2_w = (const float*)d_in[14];
    const float* ff2_b = (const float*)d_in[15];
    const float* ln2_g = (const float*)d_in[16];
    const float* ln2_b = (const float*)d_in[17];

    float* x = (float*)d_out;  // [2048][256]

    const size_t BM_OFF   = 0;
    const size_t FC1T_OFF = 10240;
    const size_t FC1T_BYTES = (size_t)F_TOT * FFDIM * 2;
    const size_t QKVT_OFF = FC1T_OFF + FC1T_BYTES;
    const size_t QKVT_BYTES = (size_t)2 * 768 * 256 * 2;
    const size_t OUTT_OFF = QKVT_OFF + QKVT_BYTES;
    const size_t OUTT_BYTES = (size_t)2 * 256 * 256 * 2;
    const size_t FF1T_OFF = OUTT_OFF + OUTT_BYTES;
    const size_t FF1T_BYTES = (size_t)2 * 1024 * 256 * 2;
    const size_t FF2T_OFF = FF1T_OFF + FF1T_BYTES;
    const size_t FF2T_BYTES = (size_t)2 * 256 * 1024 * 2;
    const size_t ATTN_OFF = FF2T_OFF + FF2T_BYTES;
    const size_t ATTN_BYTES = (size_t)NTOK * DMODEL * 4;
    const size_t FAST_BYTES = ATTN_OFF + ATTN_BYTES;

    if (ws_size >= FAST_BYTES) {
        unsigned int*   bm   = (unsigned int*)((char*)d_ws + BM_OFF);
        unsigned short* fc1T = (unsigned short*)((char*)d_ws + FC1T_OFF);
        unsigned short* qkvF = (unsigned short*)((char*)d_ws + QKVT_OFF);
        unsigned short* outF = (unsigned short*)((char*)d_ws + OUTT_OFF);
        unsigned short* ff1F = (unsigned short*)((char*)d_ws + FF1T_OFF);
        unsigned short* ff2F = (unsigned short*)((char*)d_ws + FF2T_OFF);
        float* attn_raw = (float*)((char*)d_ws + ATTN_OFF);

        hipMemsetAsync((void*)bm, 0, 10240, stream);
        mark_feats_par<<<56, 256, 0, stream>>>(word_idx, ngram_idx, bm);
        transpose_cvt<<<8768, 256, 0, stream>>>(
            fc1_w, fc1T, bm, qkv_w, out_w, ff1_w, ff2_w, qkvF, outF, ff1F, ff2F);
        embed_gather<<<NTOK / 8, 256, 0, stream>>>(word_idx, ngram_idx, fc1T,
                                                   fc1_b, fc2_w, fc2_b, x);

        for (int i = 0; i < 2; ++i) {
            fused_qkv_attn<<<32 * NHEAD, 512, 0, stream>>>(
                x, qkvF + (long)i * 768 * 256, qkv_b + i * 768, attn_raw);

            outln_ffn<<<NTOK / 16, 512, 0, stream>>>(
                attn_raw, outF + (long)i * 256 * 256, out_b + i * 256,
                ln1_g + i * 256, ln1_b + i * 256,
                ff1F + (long)i * 1024 * 256, ff1_b + i * 1024,
                ff2F + (long)i * 256 * 1024, ff2_b + i * 256,
                ln2_g + i * 256, ln2_b + i * 256, x);
        }
    } else {
        float* wsf      = (float*)d_ws;
        float* qkvbuf   = wsf;
        float* attn_raw = qkvbuf + 2048 * 768;
        float* obuf     = attn_raw + 2048 * 256;
        float* ffbuf    = obuf + 2048 * 256;

        embed_kernel<<<NTOK / 8, 256, 0, stream>>>(word_idx, ngram_idx, fc1_w,
                                                   fc1_b, fc2_w, fc2_b, x);
        for (int i = 0; i < 2; ++i) {
            gemm_bias<false><<<dim3(768 / 64, NTOK / 64), 256, 0, stream>>>(
                x, qkv_w + (long)i * 768 * 256, qkv_b + i * 768, qkvbuf,
                NTOK, 768, 256);
            attn_kernel<<<32 * NHEAD, 256, 0, stream>>>(qkvbuf, attn_raw);
            gemm_bias<false><<<dim3(256 / 64, NTOK / 64), 256, 0, stream>>>(
                attn_raw, out_w + (long)i * 256 * 256, out_b + i * 256, obuf,
                NTOK, 256, 256);
            add_ln_kernel<<<NTOK / 4, 256, 0, stream>>>(x, obuf, ln1_g + i * 256,
                                                        ln1_b + i * 256, x);
            gemm_bias<true><<<dim3(1024 / 64, NTOK / 64), 256, 0, stream>>>(
                x, ff1_w + (long)i * 1024 * 256, ff1_b + i * 1024, ffbuf,
                NTOK, 1024, 256);
            gemm_bias<false><<<dim3(256 / 64, NTOK / 64), 256, 0, stream>>>(
                ffbuf, ff2_w + (long)i * 256 * 1024, ff2_b + i * 256, obuf,
                NTOK, 256, 1024);
            add_ln_kernel<<<NTOK / 4, 256, 0, stream>>>(x, obuf, ln2_g + i * 256,
                                                        ln2_b + i * 256, x);
        }
    }
}